// Round 8
// baseline (318.604 us; speedup 1.0000x reference)
//
#include <hip/hip_runtime.h>
#include <hip/hip_bf16.h>
#include <hip/hip_cooperative_groups.h>

namespace cg = cooperative_groups;

#define NROW 8192
#define DIM_IN 256
#define DIMK 64
#define NDIM 192
#define NEDGE 262144
#define CAP 128           // bucket capacity; mean deg 32, sigma 5.7 -> 17-sigma

using bf16 = __hip_bfloat16;
typedef _Float16 f16;
typedef _Float16 f16x8 __attribute__((ext_vector_type(8)));
typedef _Float16 f16x4 __attribute__((ext_vector_type(4)));
typedef float f32x4 __attribute__((ext_vector_type(4)));
typedef unsigned short u16x8 __attribute__((ext_vector_type(8)));

__device__ __forceinline__ float b2f(bf16 x) { return __bfloat162float(x); }
__device__ __forceinline__ float us2f(unsigned short u) {
    return __uint_as_float(((unsigned)u) << 16);
}
// Wave-internal LDS fence (guide rule #18).
__device__ __forceinline__ void wave_sync() {
    asm volatile("s_waitcnt lgkmcnt(0)" ::: "memory");
    __builtin_amdgcn_sched_barrier(0);
}

// Per-wave dtype probes (verified rounds 2-6).
__device__ __forceinline__ int probe_isb(const unsigned short* xw, int lane) {
    int ex = (xw[lane] >> 7) & 0xFF;
    unsigned long long b = __ballot(ex >= 100 && ex <= 140);
    return (__popcll(b) >= 56) ? 1 : 0;
}
__device__ __forceinline__ int probe_is64(const int* ei, int lane) {
    unsigned long long b = __ballot(ei[2 * lane + 1] != 0);
    return (b == 0ULL) ? 1 : 0;
}
__device__ __forceinline__ int src_at(const int* p, int e, int is64) {
    return is64 ? p[2 * e] : p[e];
}
__device__ __forceinline__ int dst_at(const int* p, int e, int is64) {
    return is64 ? p[2 * (NEDGE + e)] : p[NEDGE + e];
}

// Load 8 consecutive x elems (fp32 or bf16) as f16x8 MFMA fragment slice.
__device__ __forceinline__ f16x8 ldcvt(const void* x, size_t off, int isb) {
    f16x8 r;
    if (isb) {
        u16x8 u = *(const u16x8*)((const unsigned short*)x + off);
        #pragma unroll
        for (int i = 0; i < 8; ++i) r[i] = (f16)us2f(u[i]);
    } else {
        float4 f0 = *(const float4*)((const float*)x + off);
        float4 f1 = *(const float4*)((const float*)x + off + 4);
        r[0] = (f16)f0.x; r[1] = (f16)f0.y; r[2] = (f16)f0.z; r[3] = (f16)f0.w;
        r[4] = (f16)f1.x; r[5] = (f16)f1.y; r[6] = (f16)f1.z; r[7] = (f16)f1.w;
    }
    return r;
}

// ---- shared device subroutines ---------------------------------------------
// 16-row x 192-col projection tile (4 waves, wave = 48-col group); x converted
// inline. Round-3..6-verified MFMA structure, m89-verified C/D layout.
__device__ __forceinline__ void proj_tile16(
    const void* x, const f16* wt, const void* bq, const void* bk,
    const void* bv, int isb, int r0, int wave, int lane,
    f16* qh, f16* kh, f16* vh)
{
    int n0 = wave * 48;
    int lr = lane & 15;
    int lk = (lane >> 4) * 8;

    f32x4 acc0 = {0.f, 0.f, 0.f, 0.f}, acc1 = acc0, acc2 = acc0;
    size_t abase = (size_t)(r0 + lr) * DIM_IN + lk;
    const f16* bp = wt + (size_t)(n0 + lr) * DIM_IN + lk;

    #pragma unroll
    for (int ks = 0; ks < 8; ++ks) {
        f16x8 a  = ldcvt(x, abase + ks * 32, isb);
        f16x8 b0 = *(const f16x8*)(bp + ks * 32);
        f16x8 b1 = *(const f16x8*)(bp + 16 * DIM_IN + ks * 32);
        f16x8 b2 = *(const f16x8*)(bp + 32 * DIM_IN + ks * 32);
        acc0 = __builtin_amdgcn_mfma_f32_16x16x32_f16(a, b0, acc0, 0, 0, 0);
        acc1 = __builtin_amdgcn_mfma_f32_16x16x32_f16(a, b1, acc1, 0, 0, 0);
        acc2 = __builtin_amdgcn_mfma_f32_16x16x32_f16(a, b2, acc2, 0, 0, 0);
    }

    #pragma unroll
    for (int tt = 0; tt < 3; ++tt) {
        f32x4 a = (tt == 0) ? acc0 : (tt == 1) ? acc1 : acc2;
        int d = n0 + tt * 16 + lr;
        int mat = d >> 6, dd = d & 63;
        const void* bb = (mat == 0) ? bq : (mat == 1) ? bk : bv;
        float bias = isb ? b2f(((const bf16*)bb)[dd]) : ((const float*)bb)[dd];
        f16* o = (mat == 0) ? qh : (mat == 1) ? kh : vh;
        #pragma unroll
        for (int j = 0; j < 4; ++j) {
            int r = r0 + (lane >> 4) * 4 + j;
            o[(size_t)r * DIMK + dd] = (f16)(a[j] + bias);
        }
    }
}

// One attention row per wave. bm/nb/sc are this wave's LDS slices.
// Bitmap dedup (matches adj.set(1.0)); ascending emission -> deterministic.
__device__ __forceinline__ void attn_row(
    const f16* qh, const f16* kh, const f16* vh, const int* cursor,
    const unsigned short* bucket, float* out, int row, int lane,
    unsigned* bm, unsigned short* nb, float* sc)
{
    *(uint4*)(bm + 4 * lane) = make_uint4(0u, 0u, 0u, 0u);
    wave_sync();

    int deg = cursor[row];
    if (deg > CAP) deg = CAP;
    const unsigned short* bk_ = bucket + (size_t)row * CAP;
    for (int e = lane; e < deg; e += 64) {
        int j = bk_[e];
        atomicOr(&bm[j >> 5], 1u << (j & 31));
    }
    wave_sync();

    uint4 wv = *(const uint4*)(bm + 4 * lane);
    int pc = __popc(wv.x) + __popc(wv.y) + __popc(wv.z) + __popc(wv.w);
    int incl = pc;
    #pragma unroll
    for (int o = 1; o < 64; o <<= 1) {
        int n = __shfl_up(incl, o);
        if (lane >= o) incl += n;
    }
    int nn = __shfl(incl, 63);
    int idx = incl - pc;
    unsigned wrds[4] = {wv.x, wv.y, wv.z, wv.w};
    #pragma unroll
    for (int wi = 0; wi < 4; ++wi) {
        unsigned wb = wrds[wi];
        int boff = 128 * lane + 32 * wi;
        while (wb) {
            int b = __ffs(wb) - 1;
            wb &= wb - 1;
            nb[idx++] = (unsigned short)(boff + b);
        }
    }
    wave_sync();

    if (nn == 0) {                              // P ~ 1e-10 guard
        out[(size_t)row * DIMK + lane] = 0.f;
        return;
    }

    int g = lane >> 4, gl = lane & 15;
    f16x4 qh4 = *(const f16x4*)(qh + (size_t)row * DIMK + 4 * gl);
    float q0 = (float)qh4.x, q1 = (float)qh4.y,
          q2 = (float)qh4.z, q3 = (float)qh4.w;
    for (int i = g; i < nn; i += 4) {
        int j = nb[i];
        f16x4 kk = *(const f16x4*)(kh + (size_t)j * DIMK + 4 * gl);
        float d = q0 * (float)kk.x + q1 * (float)kk.y
                + q2 * (float)kk.z + q3 * (float)kk.w;
        #pragma unroll
        for (int o = 1; o < 16; o <<= 1) d += __shfl_xor(d, o);
        if (gl == 0) sc[i] = d * 0.125f;        // 1/sqrt(64)
    }
    wave_sync();

    float s0 = (lane < nn) ? sc[lane] : -INFINITY;
    float s1 = (lane + 64 < nn) ? sc[lane + 64] : -INFINITY;
    float mx = fmaxf(s0, s1);
    #pragma unroll
    for (int o = 1; o < 64; o <<= 1) mx = fmaxf(mx, __shfl_xor(mx, o));
    float w0 = (lane < nn) ? __expf(s0 - mx) : 0.f;
    float w1 = (lane + 64 < nn) ? __expf(s1 - mx) : 0.f;
    if (lane < nn) sc[lane] = w0;
    if (lane + 64 < nn) sc[lane + 64] = w1;
    float sm = w0 + w1;
    #pragma unroll
    for (int o = 1; o < 64; o <<= 1) sm += __shfl_xor(sm, o);
    wave_sync();

    float acc = 0.f;
    int i = 0;
    for (; i + 4 <= nn; i += 4) {
        int j0 = nb[i], j1 = nb[i + 1], j2 = nb[i + 2], j3 = nb[i + 3];
        float v0 = (float)vh[(size_t)j0 * DIMK + lane];
        float v1 = (float)vh[(size_t)j1 * DIMK + lane];
        float v2 = (float)vh[(size_t)j2 * DIMK + lane];
        float v3 = (float)vh[(size_t)j3 * DIMK + lane];
        acc = fmaf(sc[i], v0, acc);
        acc = fmaf(sc[i + 1], v1, acc);
        acc = fmaf(sc[i + 2], v2, acc);
        acc = fmaf(sc[i + 3], v3, acc);
    }
    for (; i < nn; ++i)
        acc = fmaf(sc[i], (float)vh[(size_t)nb[i] * DIMK + lane], acc);

    out[(size_t)row * DIMK + lane] = acc / sm;
}

// ---------------------------------------------------------------------------
// Cooperative single-node kernel: 512 blocks x 256 threads, 2 blocks/CU
// guaranteed (launch_bounds(256,2) -> VGPR<=256; LDS 7KB). Phases:
// A: zero cursor + pack WT | sync | B: proj 16-row tile + scatter 512 edges
// per block | sync | C: attention, 16 rows/block (4 passes x 4 waves).
// threadfence() around syncs: per-XCD L2 non-coherence (guide G16).
__global__ __launch_bounds__(256, 2) void fused_coop_kernel(
    const void* __restrict__ x, const int* __restrict__ ei,
    const void* __restrict__ Wq, const void* __restrict__ bq,
    const void* __restrict__ Wk, const void* __restrict__ bk,
    const void* __restrict__ Wv, const void* __restrict__ bv,
    f16* __restrict__ wt, int* __restrict__ cursor,
    unsigned short* __restrict__ bucket,
    f16* __restrict__ qh, f16* __restrict__ kh, f16* __restrict__ vh,
    float* __restrict__ out)
{
    cg::grid_group grid = cg::this_grid();
    int t = threadIdx.x, lane = t & 63, wave = t >> 6;
    int isb = probe_isb((const unsigned short*)x, lane);

    // ---- Phase A ----
    int gid = blockIdx.x * 256 + t;              // < 131072
    if (gid < NROW) cursor[gid] = 0;
    int wi = gid - NROW;
    if (wi >= 0 && wi < NDIM * DIM_IN) {
        int d = wi >> 8, c = wi & 255;
        int mat = d >> 6, dd = d & 63;
        const void* W = (mat == 0) ? Wq : (mat == 1) ? Wk : Wv;
        float val = isb ? b2f(((const bf16*)W)[c * DIMK + dd])
                        : ((const float*)W)[c * DIMK + dd];
        wt[d * DIM_IN + c] = (f16)val;
    }
    __threadfence();
    grid.sync();
    __threadfence();

    // ---- Phase B: proj + scatter in every block ----
    proj_tile16(x, wt, bq, bk, bv, isb, blockIdx.x * 16, wave, lane,
                qh, kh, vh);
    {
        int is64 = probe_is64(ei, lane);
        int e0 = blockIdx.x * 512 + t;
        #pragma unroll
        for (int ii = 0; ii < 2; ++ii) {
            int e = e0 + ii * 256;
            int r = src_at(ei, e, is64) & (NROW - 1);
            int c = dst_at(ei, e, is64) & (NROW - 1);
            int pos = atomicAdd(&cursor[r], 1);
            if (pos < CAP) bucket[(size_t)r * CAP + pos] = (unsigned short)c;
        }
    }
    __threadfence();
    grid.sync();
    __threadfence();

    // ---- Phase C: attention ----
    __shared__ unsigned bm_all[4][NROW / 32];
    __shared__ unsigned short nb_all[4][CAP];
    __shared__ float sc_all[4][CAP];
    #pragma unroll
    for (int pass = 0; pass < 4; ++pass) {
        int row = pass * 2048 + blockIdx.x * 4 + wave;
        attn_row(qh, kh, vh, cursor, bucket, out, row, lane,
                 bm_all[wave], nb_all[wave], sc_all[wave]);
    }
}

// ---------------------------------------------------------------------------
// Fallback 3-node path (round-4/6-verified structure).
__global__ __launch_bounds__(256) void prep_kernel(
    const void* __restrict__ x,
    const void* __restrict__ Wq, const void* __restrict__ Wk,
    const void* __restrict__ Wv,
    f16* __restrict__ wt, int* __restrict__ cursor)
{
    int t = threadIdx.x, lane = t & 63;
    int gid = blockIdx.x * 256 + t;              // grid 224 -> gid < 57344
    if (gid < NROW) cursor[gid] = 0;
    int wi = gid - NROW;
    if (wi >= 0 && wi < NDIM * DIM_IN) {
        int isb = probe_isb((const unsigned short*)x, lane);
        int d = wi >> 8, c = wi & 255;
        int mat = d >> 6, dd = d & 63;
        const void* W = (mat == 0) ? Wq : (mat == 1) ? Wk : Wv;
        float val = isb ? b2f(((const bf16*)W)[c * DIMK + dd])
                        : ((const float*)W)[c * DIMK + dd];
        wt[d * DIM_IN + c] = (f16)val;
    }
}

__global__ __launch_bounds__(256) void proj_scatter_kernel(
    const void* __restrict__ x, const f16* __restrict__ wt,
    const void* __restrict__ bq, const void* __restrict__ bk,
    const void* __restrict__ bv, const int* __restrict__ ei,
    int* __restrict__ cursor, unsigned short* __restrict__ bucket,
    f16* __restrict__ qh, f16* __restrict__ kh, f16* __restrict__ vh)
{
    int t = threadIdx.x, lane = t & 63, wave = t >> 6;
    int isb = probe_isb((const unsigned short*)x, lane);
    int is64 = probe_is64(ei, lane);
    int e0 = blockIdx.x * 512 + t;               // grid 512
    #pragma unroll
    for (int ii = 0; ii < 2; ++ii) {
        int e = e0 + ii * 256;
        int r = src_at(ei, e, is64) & (NROW - 1);
        int c = dst_at(ei, e, is64) & (NROW - 1);
        int pos = atomicAdd(&cursor[r], 1);
        if (pos < CAP) bucket[(size_t)r * CAP + pos] = (unsigned short)c;
    }
    proj_tile16(x, wt, bq, bk, bv, isb, blockIdx.x * 16, wave, lane,
                qh, kh, vh);
}

__global__ __launch_bounds__(256) void attn_kernel(
    const f16* __restrict__ qh, const f16* __restrict__ kh,
    const f16* __restrict__ vh, const int* __restrict__ cursor,
    const unsigned short* __restrict__ bucket, float* __restrict__ out)
{
    __shared__ unsigned bm_all[4][NROW / 32];
    __shared__ unsigned short nb_all[4][CAP];
    __shared__ float sc_all[4][CAP];
    int t = threadIdx.x, lane = t & 63, wave = t >> 6;
    int row = blockIdx.x * 4 + wave;             // grid 2048
    attn_row(qh, kh, vh, cursor, bucket, out, row, lane,
             bm_all[wave], nb_all[wave], sc_all[wave]);
}

// ---------------------------------------------------------------------------
extern "C" void kernel_launch(void* const* d_in, const int* in_sizes, int n_in,
                              void* d_out, int out_size, void* d_ws, size_t ws_size,
                              hipStream_t stream)
{
    const void* x  = d_in[0];
    const int*  ei = (const int*)d_in[1];
    const void* Wq = d_in[2];
    const void* bq = d_in[3];
    const void* Wk = d_in[4];
    const void* bk = d_in[5];
    const void* Wv = d_in[6];
    const void* bv = d_in[7];
    float* out = (float*)d_out;

    // Workspace (~5.4 MB): wt 96KB | qh,kh,vh 1MB each | cursor 32KB | bucket 2MB
    char* W8 = (char*)d_ws;
    f16* wt = (f16*)W8;
    f16* qh = (f16*)(W8 + 98304);
    f16* kh = qh + (size_t)NROW * DIMK;
    f16* vh = kh + (size_t)NROW * DIMK;
    int* cursor = (int*)(vh + (size_t)NROW * DIMK);
    unsigned short* bucket = (unsigned short*)(cursor + NROW);
    size_t need = (size_t)((char*)(bucket + (size_t)NROW * CAP) - W8);
    if (ws_size < need) return;

    void* args[] = {
        (void*)&x, (void*)&ei, (void*)&Wq, (void*)&bq, (void*)&Wk, (void*)&bk,
        (void*)&Wv, (void*)&bv, (void*)&wt, (void*)&cursor, (void*)&bucket,
        (void*)&qh, (void*)&kh, (void*)&vh, (void*)&out
    };
    hipError_t err = hipLaunchCooperativeKernel(
        (const void*)fused_coop_kernel, dim3(512), dim3(256), args, 0, stream);
    if (err != hipSuccess) {
        // Fallback: equivalent 3-node path.
        prep_kernel<<<224, 256, 0, stream>>>(x, Wq, Wk, Wv, wt, cursor);
        proj_scatter_kernel<<<512, 256, 0, stream>>>(x, wt, bq, bk, bv, ei,
                                                     cursor, bucket,
                                                     qh, kh, vh);
        attn_kernel<<<2048, 256, 0, stream>>>(qh, kh, vh, cursor, bucket, out);
    }
}

// Round 9
// 47.415 us; speedup vs baseline: 6.7195x; 6.7195x over previous
//
#include <hip/hip_runtime.h>
#include <hip/hip_bf16.h>

#define NROW 8192
#define DIM_IN 256
#define DIMK 64
#define NDIM 192
#define NEDGE 262144
#define CAP 128           // bucket capacity; mean deg 32, sigma 5.7 -> 17-sigma

using bf16 = __hip_bfloat16;
typedef _Float16 f16;
typedef _Float16 f16x8 __attribute__((ext_vector_type(8)));
typedef _Float16 f16x4 __attribute__((ext_vector_type(4)));
typedef float f32x4 __attribute__((ext_vector_type(4)));
typedef unsigned short u16x8 __attribute__((ext_vector_type(8)));

__device__ __forceinline__ float b2f(bf16 x) { return __bfloat162float(x); }
__device__ __forceinline__ float us2f(unsigned short u) {
    return __uint_as_float(((unsigned)u) << 16);
}
// Wave-internal LDS fence (guide rule #18).
__device__ __forceinline__ void wave_sync() {
    asm volatile("s_waitcnt lgkmcnt(0)" ::: "memory");
    __builtin_amdgcn_sched_barrier(0);
}

// Per-wave dtype probes (verified rounds 2-8).
__device__ __forceinline__ int probe_isb(const unsigned short* xw, int lane) {
    int ex = (xw[lane] >> 7) & 0xFF;
    unsigned long long b = __ballot(ex >= 100 && ex <= 140);
    return (__popcll(b) >= 56) ? 1 : 0;
}
__device__ __forceinline__ int probe_is64(const int* ei, int lane) {
    unsigned long long b = __ballot(ei[2 * lane + 1] != 0);
    return (b == 0ULL) ? 1 : 0;
}
__device__ __forceinline__ int src_at(const int* p, int e, int is64) {
    return is64 ? p[2 * e] : p[e];
}
__device__ __forceinline__ int dst_at(const int* p, int e, int is64) {
    return is64 ? p[2 * (NEDGE + e)] : p[NEDGE + e];
}

// Load 8 consecutive x elems (fp32 or bf16) as f16x8 MFMA fragment slice.
__device__ __forceinline__ f16x8 ldcvt(const void* x, size_t off, int isb) {
    f16x8 r;
    if (isb) {
        u16x8 u = *(const u16x8*)((const unsigned short*)x + off);
        #pragma unroll
        for (int i = 0; i < 8; ++i) r[i] = (f16)us2f(u[i]);
    } else {
        float4 f0 = *(const float4*)((const float*)x + off);
        float4 f1 = *(const float4*)((const float*)x + off + 4);
        r[0] = (f16)f0.x; r[1] = (f16)f0.y; r[2] = (f16)f0.z; r[3] = (f16)f0.w;
        r[4] = (f16)f1.x; r[5] = (f16)f1.y; r[6] = (f16)f1.z; r[7] = (f16)f1.w;
    }
    return r;
}

// 16-row x 192-col projection tile (4 waves, wave = 48-col group); x converted
// inline. HW-verified round 8 (coop kernel passed, absmax 0.0078).
__device__ __forceinline__ void proj_tile16(
    const void* x, const f16* wt, const void* bq, const void* bk,
    const void* bv, int isb, int r0, int wave, int lane,
    f16* qh, f16* kh, f16* vh)
{
    int n0 = wave * 48;
    int lr = lane & 15;
    int lk = (lane >> 4) * 8;

    f32x4 acc0 = {0.f, 0.f, 0.f, 0.f}, acc1 = acc0, acc2 = acc0;
    size_t abase = (size_t)(r0 + lr) * DIM_IN + lk;
    const f16* bp = wt + (size_t)(n0 + lr) * DIM_IN + lk;

    #pragma unroll
    for (int ks = 0; ks < 8; ++ks) {
        f16x8 a  = ldcvt(x, abase + ks * 32, isb);
        f16x8 b0 = *(const f16x8*)(bp + ks * 32);
        f16x8 b1 = *(const f16x8*)(bp + 16 * DIM_IN + ks * 32);
        f16x8 b2 = *(const f16x8*)(bp + 32 * DIM_IN + ks * 32);
        acc0 = __builtin_amdgcn_mfma_f32_16x16x32_f16(a, b0, acc0, 0, 0, 0);
        acc1 = __builtin_amdgcn_mfma_f32_16x16x32_f16(a, b1, acc1, 0, 0, 0);
        acc2 = __builtin_amdgcn_mfma_f32_16x16x32_f16(a, b2, acc2, 0, 0, 0);
    }

    #pragma unroll
    for (int tt = 0; tt < 3; ++tt) {
        f32x4 a = (tt == 0) ? acc0 : (tt == 1) ? acc1 : acc2;
        int d = n0 + tt * 16 + lr;
        int mat = d >> 6, dd = d & 63;
        const void* bb = (mat == 0) ? bq : (mat == 1) ? bk : bv;
        float bias = isb ? b2f(((const bf16*)bb)[dd]) : ((const float*)bb)[dd];
        f16* o = (mat == 0) ? qh : (mat == 1) ? kh : vh;
        #pragma unroll
        for (int j = 0; j < 4; ++j) {
            int r = r0 + (lane >> 4) * 4 + j;   // m89-verified C/D layout
            o[(size_t)r * DIMK + dd] = (f16)(a[j] + bias);
        }
    }
}

// One attention row per wave (HW-verified round 8). Bitmap dedup matches
// adj.set(1.0); ascending emission -> deterministic fp sums across replays.
__device__ __forceinline__ void attn_row(
    const f16* qh, const f16* kh, const f16* vh, const int* cursor,
    const unsigned short* bucket, float* out, int row, int lane,
    unsigned* bm, unsigned short* nb, float* sc)
{
    *(uint4*)(bm + 4 * lane) = make_uint4(0u, 0u, 0u, 0u);
    wave_sync();

    int deg = cursor[row];
    if (deg > CAP) deg = CAP;
    const unsigned short* bk_ = bucket + (size_t)row * CAP;
    for (int e = lane; e < deg; e += 64) {
        int j = bk_[e];
        atomicOr(&bm[j >> 5], 1u << (j & 31));
    }
    wave_sync();

    uint4 wv = *(const uint4*)(bm + 4 * lane);
    int pc = __popc(wv.x) + __popc(wv.y) + __popc(wv.z) + __popc(wv.w);
    int incl = pc;
    #pragma unroll
    for (int o = 1; o < 64; o <<= 1) {
        int n = __shfl_up(incl, o);
        if (lane >= o) incl += n;
    }
    int nn = __shfl(incl, 63);
    int idx = incl - pc;
    unsigned wrds[4] = {wv.x, wv.y, wv.z, wv.w};
    #pragma unroll
    for (int wi = 0; wi < 4; ++wi) {
        unsigned wb = wrds[wi];
        int boff = 128 * lane + 32 * wi;
        while (wb) {
            int b = __ffs(wb) - 1;
            wb &= wb - 1;
            nb[idx++] = (unsigned short)(boff + b);
        }
    }
    wave_sync();

    if (nn == 0) {                              // P ~ 1e-10 guard
        out[(size_t)row * DIMK + lane] = 0.f;
        return;
    }

    int g = lane >> 4, gl = lane & 15;
    f16x4 qh4 = *(const f16x4*)(qh + (size_t)row * DIMK + 4 * gl);
    float q0 = (float)qh4.x, q1 = (float)qh4.y,
          q2 = (float)qh4.z, q3 = (float)qh4.w;
    for (int i = g; i < nn; i += 4) {
        int j = nb[i];
        f16x4 kk = *(const f16x4*)(kh + (size_t)j * DIMK + 4 * gl);
        float d = q0 * (float)kk.x + q1 * (float)kk.y
                + q2 * (float)kk.z + q3 * (float)kk.w;
        #pragma unroll
        for (int o = 1; o < 16; o <<= 1) d += __shfl_xor(d, o);
        if (gl == 0) sc[i] = d * 0.125f;        // 1/sqrt(64)
    }
    wave_sync();

    float s0 = (lane < nn) ? sc[lane] : -INFINITY;
    float s1 = (lane + 64 < nn) ? sc[lane + 64] : -INFINITY;
    float mx = fmaxf(s0, s1);
    #pragma unroll
    for (int o = 1; o < 64; o <<= 1) mx = fmaxf(mx, __shfl_xor(mx, o));
    float w0 = (lane < nn) ? __expf(s0 - mx) : 0.f;
    float w1 = (lane + 64 < nn) ? __expf(s1 - mx) : 0.f;
    if (lane < nn) sc[lane] = w0;
    if (lane + 64 < nn) sc[lane + 64] = w1;
    float sm = w0 + w1;
    #pragma unroll
    for (int o = 1; o < 64; o <<= 1) sm += __shfl_xor(sm, o);
    wave_sync();

    float acc = 0.f;
    int i = 0;
    for (; i + 4 <= nn; i += 4) {
        int j0 = nb[i], j1 = nb[i + 1], j2 = nb[i + 2], j3 = nb[i + 3];
        float v0 = (float)vh[(size_t)j0 * DIMK + lane];
        float v1 = (float)vh[(size_t)j1 * DIMK + lane];
        float v2 = (float)vh[(size_t)j2 * DIMK + lane];
        float v3 = (float)vh[(size_t)j3 * DIMK + lane];
        acc = fmaf(sc[i], v0, acc);
        acc = fmaf(sc[i + 1], v1, acc);
        acc = fmaf(sc[i + 2], v2, acc);
        acc = fmaf(sc[i + 3], v3, acc);
    }
    for (; i < nn; ++i)
        acc = fmaf(sc[i], (float)vh[(size_t)nb[i] * DIMK + lane], acc);

    out[(size_t)row * DIMK + lane] = acc / sm;
}

// ---------------------------------------------------------------------------
// Node 1: zero cursor (32 KB) + pack WT[192][256]. 224 blocks x 256.
__global__ __launch_bounds__(256) void prep_kernel(
    const void* __restrict__ x,
    const void* __restrict__ Wq, const void* __restrict__ Wk,
    const void* __restrict__ Wv,
    f16* __restrict__ wt, int* __restrict__ cursor)
{
    int t = threadIdx.x, lane = t & 63;
    int gid = blockIdx.x * 256 + t;              // < 57344
    if (gid < NROW) cursor[gid] = 0;
    int wi = gid - NROW;
    if (wi >= 0 && wi < NDIM * DIM_IN) {
        int isb = probe_isb((const unsigned short*)x, lane);
        int d = wi >> 8, c = wi & 255;
        int mat = d >> 6, dd = d & 63;
        const void* W = (mat == 0) ? Wq : (mat == 1) ? Wk : Wv;
        float val = isb ? b2f(((const bf16*)W)[c * DIMK + dd])
                        : ((const float*)W)[c * DIMK + dd];
        wt[d * DIM_IN + c] = (f16)val;
    }
}

// Node 2: edge scatter (atomics issued first, latency hides under MFMA) +
// 16-row projection tile. 512 blocks x 256 threads.
__global__ __launch_bounds__(256) void proj_scatter_kernel(
    const void* __restrict__ x, const f16* __restrict__ wt,
    const void* __restrict__ bq, const void* __restrict__ bk,
    const void* __restrict__ bv, const int* __restrict__ ei,
    int* __restrict__ cursor, unsigned short* __restrict__ bucket,
    f16* __restrict__ qh, f16* __restrict__ kh, f16* __restrict__ vh)
{
    int t = threadIdx.x, lane = t & 63, wave = t >> 6;
    int isb = probe_isb((const unsigned short*)x, lane);
    int is64 = probe_is64(ei, lane);
    int e0 = blockIdx.x * 512 + t;
    #pragma unroll
    for (int ii = 0; ii < 2; ++ii) {
        int e = e0 + ii * 256;
        int r = src_at(ei, e, is64) & (NROW - 1);
        int c = dst_at(ei, e, is64) & (NROW - 1);
        int pos = atomicAdd(&cursor[r], 1);
        if (pos < CAP) bucket[(size_t)r * CAP + pos] = (unsigned short)c;
    }
    proj_tile16(x, wt, bq, bk, bv, isb, blockIdx.x * 16, wave, lane,
                qh, kh, vh);
}

// Node 3: attention, 1 wave/row, 4 rows/block. 2048 blocks (8/CU).
__global__ __launch_bounds__(256) void attn_kernel(
    const f16* __restrict__ qh, const f16* __restrict__ kh,
    const f16* __restrict__ vh, const int* __restrict__ cursor,
    const unsigned short* __restrict__ bucket, float* __restrict__ out)
{
    __shared__ unsigned bm_all[4][NROW / 32];
    __shared__ unsigned short nb_all[4][CAP];
    __shared__ float sc_all[4][CAP];
    int t = threadIdx.x, lane = t & 63, wave = t >> 6;
    int row = blockIdx.x * 4 + wave;
    attn_row(qh, kh, vh, cursor, bucket, out, row, lane,
             bm_all[wave], nb_all[wave], sc_all[wave]);
}

// ---------------------------------------------------------------------------
extern "C" void kernel_launch(void* const* d_in, const int* in_sizes, int n_in,
                              void* d_out, int out_size, void* d_ws, size_t ws_size,
                              hipStream_t stream)
{
    const void* x  = d_in[0];
    const int*  ei = (const int*)d_in[1];
    const void* Wq = d_in[2];
    const void* bq = d_in[3];
    const void* Wk = d_in[4];
    const void* bk = d_in[5];
    const void* Wv = d_in[6];
    const void* bv = d_in[7];
    float* out = (float*)d_out;

    // Workspace (~5.4 MB): wt 96KB | qh,kh,vh 1MB each | cursor 32KB | bucket 2MB
    char* W8 = (char*)d_ws;
    f16* wt = (f16*)W8;
    f16* qh = (f16*)(W8 + 98304);
    f16* kh = qh + (size_t)NROW * DIMK;
    f16* vh = kh + (size_t)NROW * DIMK;
    int* cursor = (int*)(vh + (size_t)NROW * DIMK);
    unsigned short* bucket = (unsigned short*)(cursor + NROW);
    size_t need = (size_t)((char*)(bucket + (size_t)NROW * CAP) - W8);
    if (ws_size < need) return;

    prep_kernel<<<224, 256, 0, stream>>>(x, Wq, Wk, Wv, wt, cursor);
    proj_scatter_kernel<<<512, 256, 0, stream>>>(x, wt, bq, bk, bv, ei,
                                                 cursor, bucket, qh, kh, vh);
    attn_kernel<<<2048, 256, 0, stream>>>(qh, kh, vh, cursor, bucket, out);
}